// Round 1
// baseline (899.548 us; speedup 1.0000x reference)
//
#include <hip/hip_runtime.h>
#include <hip/hip_bf16.h>
#include <stdint.h>

#define BATCH   16384
#define HORIZON 12

// ---------- types ----------
typedef __bf16 bf16x8 __attribute__((ext_vector_type(8)));
typedef float  f32x4  __attribute__((ext_vector_type(4)));

__device__ __forceinline__ unsigned short f2bf(float f) {
  union { float f; uint32_t u; } v; v.f = f;
  uint32_t u = v.u;
  return (unsigned short)((u + 0x7FFFu + ((u >> 16) & 1u)) >> 16);
}

__device__ __forceinline__ void gload16(const void* g, void* l) {
  __builtin_amdgcn_global_load_lds(
      (const __attribute__((address_space(1))) void*)g,
      (__attribute__((address_space(3))) void*)l, 16, 0, 0);
}

__device__ __forceinline__ float sigm(float x) { return 1.0f / (1.0f + __expf(-x)); }
__device__ __forceinline__ float tanh_fast(float x) { return 1.0f - 2.0f / (__expf(2.0f * x) + 1.0f); }

// ---------- prep: cast weights/state to bf16, copy h0 to fp32 state ----------
// ranges (element idx, all /4): wih 393216 | whh 393216 | wlin 65536 | h0 8388608 | y0 4194304
__global__ void prep(const float* __restrict__ y0, const float* __restrict__ h0,
                     const float* __restrict__ wih, const float* __restrict__ whh,
                     const float* __restrict__ wlin,
                     unsigned short* __restrict__ wih_b, unsigned short* __restrict__ whh_b,
                     unsigned short* __restrict__ wlin_b,
                     float* __restrict__ hf, unsigned short* __restrict__ hb0,
                     unsigned short* __restrict__ xb) {
  const int stride = gridDim.x * blockDim.x;
  for (int i = blockIdx.x * blockDim.x + threadIdx.x; i < 3358720; i += stride) {
    const int e = i << 2;
    if (e < 393216) {
      float4 v = *(const float4*)(wih + e);
      ushort4 o; o.x = f2bf(v.x); o.y = f2bf(v.y); o.z = f2bf(v.z); o.w = f2bf(v.w);
      *(ushort4*)(wih_b + e) = o;
    } else if (e < 786432) {
      const int k = e - 393216;
      float4 v = *(const float4*)(whh + k);
      ushort4 o; o.x = f2bf(v.x); o.y = f2bf(v.y); o.z = f2bf(v.z); o.w = f2bf(v.w);
      *(ushort4*)(whh_b + k) = o;
    } else if (e < 851968) {
      const int k = e - 786432;
      float4 v = *(const float4*)(wlin + k);
      ushort4 o; o.x = f2bf(v.x); o.y = f2bf(v.y); o.z = f2bf(v.z); o.w = f2bf(v.w);
      *(ushort4*)(wlin_b + k) = o;
    } else if (e < 9240576) {
      const int k = e - 851968;
      float4 v = *(const float4*)(h0 + k);
      *(float4*)(hf + k) = v;
      ushort4 o; o.x = f2bf(v.x); o.y = f2bf(v.y); o.z = f2bf(v.z); o.w = f2bf(v.w);
      *(ushort4*)(hb0 + k) = o;
    } else {
      const int k = e - 9240576;
      float4 v = *(const float4*)(y0 + k);
      ushort4 o; o.x = f2bf(v.x); o.y = f2bf(v.y); o.z = f2bf(v.z); o.w = f2bf(v.w);
      *(ushort4*)(xb + k) = o;
    }
  }
}

// ---------- fused GRU layer step ----------
// block tile: 256 batch rows x 64 h-cols; 8 waves as 4M x 2N; wave tile 64x32.
// 4 acc streams per element: S_r = x*Wr + h*Ur, S_z = x*Wz + h*Uz, i_n = x*Wn, h_n = h*Un.
// LDS rows of 32 bf16 (64B), 16B-granule XOR swizzle key = (row>>1)&3, matched on
// pre-swizzled global source (global_load_lds writes linearly).
__global__ __launch_bounds__(512, 2) void gru_layer(
    const unsigned short* __restrict__ Xb,   // [B][256] bf16 layer input
    const unsigned short* __restrict__ Hb,   // [B][256] bf16 h_{t-1}
    unsigned short* __restrict__ Hout,       // [B][256] bf16 h_t
    float* __restrict__ Hf,                  // [B][256] fp32 h state (in/out)
    const unsigned short* __restrict__ Wih,  // [768][256] bf16
    const unsigned short* __restrict__ Whh,  // [768][256] bf16
    const float* __restrict__ bih,           // [768]
    const float* __restrict__ bhh) {         // [768]
  __shared__ unsigned short sm[896 * 32];    // X[256] | H[256] | W6[384] rows, 57344 B

  const int tid  = threadIdx.x;
  const int wave = tid >> 6;
  const int lane = tid & 63;
  const int b0 = blockIdx.x * 256;
  const int j0 = blockIdx.y * 64;
  const int mw = wave >> 1;          // 0..3
  const int nw = wave & 1;           // 0..1
  const int l15 = lane & 15;
  const int l4  = lane >> 4;         // read granule
  const int rl  = lane >> 2;         // staging local row (0..15)
  const int gq  = lane & 3;          // staging granule
  const int scol_sw = ((gq ^ ((rl >> 1) & 3)) << 4);  // swizzled byte col in 64B slice

  f32x4 sr[4][2], sz[4][2], si[4][2], sh[4][2];
#pragma unroll
  for (int a = 0; a < 4; ++a)
#pragma unroll
    for (int b = 0; b < 2; ++b) { sr[a][b] = 0.f; sz[a][b] = 0.f; si[a][b] = 0.f; sh[a][b] = 0.f; }

  for (int k0 = 0; k0 < 256; k0 += 32) {
    __syncthreads();
    const int cb = (k0 << 1) + scol_sw;   // byte col in 512B global row
    // 56 issues: 16 X + 16 H + 24 W6 (6 streams x 4), each = 16 rows x 64B
    for (int i = wave; i < 56; i += 8) {
      int grow, lrow;
      const unsigned short* gb;
      if (i < 16)      { grow = b0 + (i << 4) + rl;        gb = Xb; lrow = (i << 4); }
      else if (i < 32) { grow = b0 + ((i - 16) << 4) + rl; gb = Hb; lrow = 256 + ((i - 16) << 4); }
      else {
        const int is = i - 32;
        const int s  = is >> 2;           // stream 0..5
        const int rr = (is & 3) << 4;
        grow = (s < 3 ? s * 256 : (s - 3) * 256) + j0 + rr + rl;
        gb   = (s < 3) ? Wih : Whh;
        lrow = 512 + s * 64 + rr;
      }
      gload16((const char*)gb + (size_t)grow * 512 + cb, (void*)&sm[lrow * 32]);
    }
    __syncthreads();   // compiler drains vmcnt(0) before s_barrier

    bf16x8 ax[4], ah[4];
#pragma unroll
    for (int mt = 0; mt < 4; ++mt) {
      const int m = mw * 64 + mt * 16 + l15;
      const int idx = m * 32 + ((l4 ^ ((m >> 1) & 3)) << 3);
      ax[mt] = *(const bf16x8*)&sm[idx];
      ah[mt] = *(const bf16x8*)&sm[256 * 32 + idx];
    }
#pragma unroll
    for (int nt = 0; nt < 2; ++nt) {
      const int nc = nw * 32 + nt * 16 + l15;   // 0..63 within block's h-cols
      bf16x8 w[6];
#pragma unroll
      for (int s = 0; s < 6; ++s) {
        const int rrow = s * 64 + nc;
        const int idx = (512 + rrow) * 32 + ((l4 ^ ((rrow >> 1) & 3)) << 3);
        w[s] = *(const bf16x8*)&sm[idx];
      }
#pragma unroll
      for (int mt = 0; mt < 4; ++mt) {
        sr[mt][nt] = __builtin_amdgcn_mfma_f32_16x16x32_bf16(ax[mt], w[0], sr[mt][nt], 0, 0, 0);
        sr[mt][nt] = __builtin_amdgcn_mfma_f32_16x16x32_bf16(ah[mt], w[3], sr[mt][nt], 0, 0, 0);
        sz[mt][nt] = __builtin_amdgcn_mfma_f32_16x16x32_bf16(ax[mt], w[1], sz[mt][nt], 0, 0, 0);
        sz[mt][nt] = __builtin_amdgcn_mfma_f32_16x16x32_bf16(ah[mt], w[4], sz[mt][nt], 0, 0, 0);
        si[mt][nt] = __builtin_amdgcn_mfma_f32_16x16x32_bf16(ax[mt], w[2], si[mt][nt], 0, 0, 0);
        sh[mt][nt] = __builtin_amdgcn_mfma_f32_16x16x32_bf16(ah[mt], w[5], sh[mt][nt], 0, 0, 0);
      }
    }
  }

  // epilogue: gates in fp32, h update against fp32 state
#pragma unroll
  for (int nt = 0; nt < 2; ++nt) {
    const int j = j0 + nw * 32 + nt * 16 + l15;
    const float brz = bih[j] + bhh[j];
    const float bzz = bih[256 + j] + bhh[256 + j];
    const float bin = bih[512 + j];
    const float bhn = bhh[512 + j];
#pragma unroll
    for (int mt = 0; mt < 4; ++mt) {
#pragma unroll
      for (int r = 0; r < 4; ++r) {
        const int b = b0 + mw * 64 + mt * 16 + l4 * 4 + r;   // C/D: row=(lane>>4)*4+reg
        const size_t off = (size_t)b * 256 + j;              // C/D: col=lane&15
        const float rg = sigm(sr[mt][nt][r] + brz);
        const float zg = sigm(sz[mt][nt][r] + bzz);
        const float nn = tanh_fast(si[mt][nt][r] + bin + rg * (sh[mt][nt][r] + bhn));
        const float hold = Hf[off];
        const float hnew = (1.0f - zg) * nn + zg * hold;
        Hf[off]   = hnew;
        Hout[off] = f2bf(hnew);
      }
    }
  }
}

// ---------- output linear: y = h1 @ Wlin^T + b; writes fp32 out + bf16 next-x ----------
__global__ __launch_bounds__(512, 2) void lin_out(
    const unsigned short* __restrict__ Hin,  // [B][256] bf16
    const unsigned short* __restrict__ Wl,   // [256][256] bf16
    const float* __restrict__ blin,          // [256]
    float* __restrict__ Y,                   // [B][256] fp32 (offset by t)
    unsigned short* __restrict__ Xb) {       // [B][256] bf16 next-step input
  __shared__ unsigned short sm[320 * 32];    // H[256] | W[64] rows

  const int tid  = threadIdx.x;
  const int wave = tid >> 6;
  const int lane = tid & 63;
  const int b0 = blockIdx.x * 256;
  const int n0 = blockIdx.y * 64;
  const int mw = wave >> 1;
  const int nw = wave & 1;
  const int l15 = lane & 15;
  const int l4  = lane >> 4;
  const int rl  = lane >> 2;
  const int gq  = lane & 3;
  const int scol_sw = ((gq ^ ((rl >> 1) & 3)) << 4);

  f32x4 acc[4][2];
#pragma unroll
  for (int a = 0; a < 4; ++a) { acc[a][0] = 0.f; acc[a][1] = 0.f; }

  for (int k0 = 0; k0 < 256; k0 += 32) {
    __syncthreads();
    const int cb = (k0 << 1) + scol_sw;
    for (int i = wave; i < 20; i += 8) {
      int grow, lrow;
      const unsigned short* gb;
      if (i < 16) { grow = b0 + (i << 4) + rl; gb = Hin; lrow = (i << 4); }
      else        { const int is = i - 16; grow = n0 + (is << 4) + rl; gb = Wl; lrow = 256 + (is << 4); }
      gload16((const char*)gb + (size_t)grow * 512 + cb, (void*)&sm[lrow * 32]);
    }
    __syncthreads();

    bf16x8 a[4];
#pragma unroll
    for (int mt = 0; mt < 4; ++mt) {
      const int m = mw * 64 + mt * 16 + l15;
      a[mt] = *(const bf16x8*)&sm[m * 32 + ((l4 ^ ((m >> 1) & 3)) << 3)];
    }
#pragma unroll
    for (int nt = 0; nt < 2; ++nt) {
      const int rw = nw * 32 + nt * 16 + l15;   // 0..63 region row
      bf16x8 w = *(const bf16x8*)&sm[(256 + rw) * 32 + ((l4 ^ ((rw >> 1) & 3)) << 3)];
#pragma unroll
      for (int mt = 0; mt < 4; ++mt)
        acc[mt][nt] = __builtin_amdgcn_mfma_f32_16x16x32_bf16(a[mt], w, acc[mt][nt], 0, 0, 0);
    }
  }

#pragma unroll
  for (int nt = 0; nt < 2; ++nt) {
    const int d = n0 + nw * 32 + nt * 16 + l15;
    const float bl = blin[d];
#pragma unroll
    for (int mt = 0; mt < 4; ++mt) {
#pragma unroll
      for (int r = 0; r < 4; ++r) {
        const int b = b0 + mw * 64 + mt * 16 + l4 * 4 + r;
        const size_t off = (size_t)b * 256 + d;
        const float y = acc[mt][nt][r] + bl;
        Y[off]  = y;
        Xb[off] = f2bf(y);
      }
    }
  }
}

// ---------- launch ----------
extern "C" void kernel_launch(void* const* d_in, const int* in_sizes, int n_in,
                              void* d_out, int out_size, void* d_ws, size_t ws_size,
                              hipStream_t stream) {
  (void)in_sizes; (void)n_in; (void)out_size; (void)ws_size;
  const float* y0   = (const float*)d_in[0];
  const float* h0   = (const float*)d_in[1];
  const float* wih  = (const float*)d_in[2];
  const float* whh  = (const float*)d_in[3];
  const float* bih  = (const float*)d_in[4];
  const float* bhh  = (const float*)d_in[5];
  const float* wlin = (const float*)d_in[6];
  const float* blin = (const float*)d_in[7];
  float* out = (float*)d_out;

  // ws layout (needs ~77.2 MB)
  char* ws = (char*)d_ws;
  unsigned short* wih_b  = (unsigned short*)ws;          // 2*768*256 el
  unsigned short* whh_b  = wih_b + 393216;
  unsigned short* wlin_b = whh_b + 393216;               // 65536 el
  float*          hf     = (float*)(ws + 1703936);       // [2][B][256] fp32
  unsigned short* hb     = (unsigned short*)(ws + 1703936 + 33554432); // [2 ping][2 layer][B][256] bf16
  unsigned short* xb     = hb + 16777216;                // [B][256] bf16

  prep<<<1024, 256, 0, stream>>>(y0, h0, wih, whh, wlin, wih_b, whh_b, wlin_b, hf, hb, xb);

  const size_t HB = (size_t)BATCH * 256;
  int cur = 0;
  for (int t = 0; t < HORIZON; ++t) {
    const int nxt = cur ^ 1;
    gru_layer<<<dim3(64, 4), 512, 0, stream>>>(
        xb, hb + (size_t)(cur * 2 + 0) * HB, hb + (size_t)(nxt * 2 + 0) * HB, hf,
        wih_b, whh_b, bih, bhh);
    gru_layer<<<dim3(64, 4), 512, 0, stream>>>(
        hb + (size_t)(nxt * 2 + 0) * HB, hb + (size_t)(cur * 2 + 1) * HB,
        hb + (size_t)(nxt * 2 + 1) * HB, hf + HB,
        wih_b + 196608, whh_b + 196608, bih + 768, bhh + 768);
    lin_out<<<dim3(64, 4), 512, 0, stream>>>(
        hb + (size_t)(nxt * 2 + 1) * HB, wlin_b, blin, out + (size_t)t * HB, xb);
    cur = nxt;
  }
}

// Round 2
// 827.210 us; speedup vs baseline: 1.0874x; 1.0874x over previous
//
#include <hip/hip_runtime.h>
#include <hip/hip_bf16.h>
#include <stdint.h>

#define BATCH   16384
#define HORIZON 12

// ---------- types ----------
typedef __bf16 bf16x8 __attribute__((ext_vector_type(8)));
typedef float  f32x4  __attribute__((ext_vector_type(4)));

__device__ __forceinline__ unsigned short f2bf(float f) {
  union { float f; uint32_t u; } v; v.f = f;
  uint32_t u = v.u;
  return (unsigned short)((u + 0x7FFFu + ((u >> 16) & 1u)) >> 16);
}

__device__ __forceinline__ void gload16(const void* g, void* l) {
  __builtin_amdgcn_global_load_lds(
      (const __attribute__((address_space(1))) void*)g,
      (__attribute__((address_space(3))) void*)l, 16, 0, 0);
}

__device__ __forceinline__ float sigm(float x) { return 1.0f / (1.0f + __expf(-x)); }
__device__ __forceinline__ float tanh_fast(float x) { return 1.0f - 2.0f / (__expf(2.0f * x) + 1.0f); }

// ---------- prep: cast weights/state to bf16, copy h0 to fp32 state ----------
__global__ void prep(const float* __restrict__ y0, const float* __restrict__ h0,
                     const float* __restrict__ wih, const float* __restrict__ whh,
                     const float* __restrict__ wlin,
                     unsigned short* __restrict__ wih_b, unsigned short* __restrict__ whh_b,
                     unsigned short* __restrict__ wlin_b,
                     float* __restrict__ hf, unsigned short* __restrict__ hb0,
                     unsigned short* __restrict__ xb) {
  const int stride = gridDim.x * blockDim.x;
  for (int i = blockIdx.x * blockDim.x + threadIdx.x; i < 3358720; i += stride) {
    const int e = i << 2;
    if (e < 393216) {
      float4 v = *(const float4*)(wih + e);
      ushort4 o; o.x = f2bf(v.x); o.y = f2bf(v.y); o.z = f2bf(v.z); o.w = f2bf(v.w);
      *(ushort4*)(wih_b + e) = o;
    } else if (e < 786432) {
      const int k = e - 393216;
      float4 v = *(const float4*)(whh + k);
      ushort4 o; o.x = f2bf(v.x); o.y = f2bf(v.y); o.z = f2bf(v.z); o.w = f2bf(v.w);
      *(ushort4*)(whh_b + k) = o;
    } else if (e < 851968) {
      const int k = e - 786432;
      float4 v = *(const float4*)(wlin + k);
      ushort4 o; o.x = f2bf(v.x); o.y = f2bf(v.y); o.z = f2bf(v.z); o.w = f2bf(v.w);
      *(ushort4*)(wlin_b + k) = o;
    } else if (e < 9240576) {
      const int k = e - 851968;
      float4 v = *(const float4*)(h0 + k);
      *(float4*)(hf + k) = v;
      ushort4 o; o.x = f2bf(v.x); o.y = f2bf(v.y); o.z = f2bf(v.z); o.w = f2bf(v.w);
      *(ushort4*)(hb0 + k) = o;
    } else {
      const int k = e - 9240576;
      float4 v = *(const float4*)(y0 + k);
      ushort4 o; o.x = f2bf(v.x); o.y = f2bf(v.y); o.z = f2bf(v.z); o.w = f2bf(v.w);
      *(ushort4*)(xb + k) = o;
    }
  }
}

// ---------- fused GRU layer step (2-phase double-buffered pipeline) ----------
// block tile: 256 batch rows x 64 h-cols; 8 waves as 4M x 2N; wave tile 64x32.
// LDS: two 57344B buffers (896 rows x 64B each): X[256] | H[256] | W6[384].
// Pipeline: STAGE(next) -> ds_read+MFMA(cur) -> __syncthreads (compiler drains
// vmcnt(0) AFTER ~1500cy of compute, hiding load latency).
__global__ __launch_bounds__(512, 2) void gru_layer(
    const unsigned short* __restrict__ Xb,   // [B][256] bf16 layer input
    const unsigned short* __restrict__ Hb,   // [B][256] bf16 h_{t-1}
    unsigned short* __restrict__ Hout,       // [B][256] bf16 h_t
    float* __restrict__ Hf,                  // [B][256] fp32 h state (in/out)
    const unsigned short* __restrict__ Wih,  // [768][256] bf16
    const unsigned short* __restrict__ Whh,  // [768][256] bf16
    const float* __restrict__ bih,           // [768]
    const float* __restrict__ bhh) {         // [768]
  extern __shared__ unsigned short sm[];     // 2 x 896*32 shorts = 114688 B

  const int tid  = threadIdx.x;
  const int wave = tid >> 6;
  const int lane = tid & 63;
  const int b0 = blockIdx.x * 256;
  const int j0 = blockIdx.y * 64;
  const int mw = wave >> 1;          // 0..3
  const int nw = wave & 1;           // 0..1
  const int l15 = lane & 15;
  const int l4  = lane >> 4;         // read granule
  const int rl  = lane >> 2;         // staging local row (0..15)
  const int gq  = lane & 3;          // staging granule
  const int scol_sw = ((gq ^ ((rl >> 1) & 3)) << 4);  // swizzled byte col in 64B slice

  // precompute the 7 staging descriptors for this wave (k-independent)
  const char* gbase[7];
  int loff[7];
#pragma unroll
  for (int j = 0; j < 7; ++j) {
    const int i = wave + (j << 3);   // 0..55
    int grow, lrow;
    const unsigned short* gb;
    if (i < 16)      { grow = b0 + (i << 4) + rl;        gb = Xb; lrow = (i << 4); }
    else if (i < 32) { grow = b0 + ((i - 16) << 4) + rl; gb = Hb; lrow = 256 + ((i - 16) << 4); }
    else {
      const int is = i - 32;
      const int s  = is >> 2;        // stream 0..5
      const int rr = (is & 3) << 4;
      grow = (s < 3 ? s * 256 : (s - 3) * 256) + j0 + rr + rl;
      gb   = (s < 3) ? Wih : Whh;
      lrow = 512 + s * 64 + rr;
    }
    gbase[j] = (const char*)gb + (size_t)grow * 512;
    loff[j]  = lrow << 6;            // byte offset in LDS buffer
  }

  f32x4 sr[4][2], sz[4][2], si[4][2], sh[4][2];
#pragma unroll
  for (int a = 0; a < 4; ++a)
#pragma unroll
    for (int b = 0; b < 2; ++b) { sr[a][b] = 0.f; sz[a][b] = 0.f; si[a][b] = 0.f; sh[a][b] = 0.f; }

  // prologue: stage tile 0 into buffer 0
  {
    const int cb = scol_sw;
#pragma unroll
    for (int j = 0; j < 7; ++j) gload16(gbase[j] + cb, (char*)sm + loff[j]);
  }
  __syncthreads();

#pragma unroll
  for (int k = 0; k < 8; ++k) {
    // stage next tile into the other buffer (issued BEFORE compute)
    if (k < 7) {
      const int cb = ((k + 1) << 6) + scol_sw;
      char* lb = (char*)sm + ((k + 1) & 1) * 57344;
#pragma unroll
      for (int j = 0; j < 7; ++j) gload16(gbase[j] + cb, lb + loff[j]);
    }

    const int bb = (k & 1) * 28672;  // element offset of current buffer

    bf16x8 ax[4], ah[4];
#pragma unroll
    for (int mt = 0; mt < 4; ++mt) {
      const int m = mw * 64 + mt * 16 + l15;
      const int idx = m * 32 + ((l4 ^ ((m >> 1) & 3)) << 3);
      ax[mt] = *(const bf16x8*)&sm[bb + idx];
      ah[mt] = *(const bf16x8*)&sm[bb + 256 * 32 + idx];
    }
#pragma unroll
    for (int nt = 0; nt < 2; ++nt) {
      const int nc = nw * 32 + nt * 16 + l15;
      bf16x8 w[6];
#pragma unroll
      for (int s = 0; s < 6; ++s) {
        const int rrow = s * 64 + nc;
        const int idx = (512 + rrow) * 32 + ((l4 ^ ((rrow >> 1) & 3)) << 3);
        w[s] = *(const bf16x8*)&sm[bb + idx];
      }
#pragma unroll
      for (int mt = 0; mt < 4; ++mt) {
        sr[mt][nt] = __builtin_amdgcn_mfma_f32_16x16x32_bf16(ax[mt], w[0], sr[mt][nt], 0, 0, 0);
        sr[mt][nt] = __builtin_amdgcn_mfma_f32_16x16x32_bf16(ah[mt], w[3], sr[mt][nt], 0, 0, 0);
        sz[mt][nt] = __builtin_amdgcn_mfma_f32_16x16x32_bf16(ax[mt], w[1], sz[mt][nt], 0, 0, 0);
        sz[mt][nt] = __builtin_amdgcn_mfma_f32_16x16x32_bf16(ah[mt], w[4], sz[mt][nt], 0, 0, 0);
        si[mt][nt] = __builtin_amdgcn_mfma_f32_16x16x32_bf16(ax[mt], w[2], si[mt][nt], 0, 0, 0);
        sh[mt][nt] = __builtin_amdgcn_mfma_f32_16x16x32_bf16(ah[mt], w[5], sh[mt][nt], 0, 0, 0);
      }
    }
    __syncthreads();   // drains vmcnt(0) here — AFTER the MFMA cluster
  }

  // epilogue: gates in fp32, h update against fp32 state
#pragma unroll
  for (int nt = 0; nt < 2; ++nt) {
    const int j = j0 + nw * 32 + nt * 16 + l15;
    const float brz = bih[j] + bhh[j];
    const float bzz = bih[256 + j] + bhh[256 + j];
    const float bin = bih[512 + j];
    const float bhn = bhh[512 + j];
#pragma unroll
    for (int mt = 0; mt < 4; ++mt) {
#pragma unroll
      for (int r = 0; r < 4; ++r) {
        const int b = b0 + mw * 64 + mt * 16 + l4 * 4 + r;   // C/D: row=(lane>>4)*4+reg
        const size_t off = (size_t)b * 256 + j;              // C/D: col=lane&15
        const float rg = sigm(sr[mt][nt][r] + brz);
        const float zg = sigm(sz[mt][nt][r] + bzz);
        const float nn = tanh_fast(si[mt][nt][r] + bin + rg * (sh[mt][nt][r] + bhn));
        const float hold = Hf[off];
        const float hnew = (1.0f - zg) * nn + zg * hold;
        Hf[off]   = hnew;
        Hout[off] = f2bf(hnew);
      }
    }
  }
}

// ---------- output linear (2-phase double-buffered) ----------
__global__ __launch_bounds__(512, 2) void lin_out(
    const unsigned short* __restrict__ Hin,  // [B][256] bf16
    const unsigned short* __restrict__ Wl,   // [256][256] bf16
    const float* __restrict__ blin,          // [256]
    float* __restrict__ Y,                   // [B][256] fp32 (offset by t)
    unsigned short* __restrict__ Xb) {       // [B][256] bf16 next-step input
  __shared__ unsigned short sm[2 * 320 * 32];  // 2 x 20480 B

  const int tid  = threadIdx.x;
  const int wave = tid >> 6;
  const int lane = tid & 63;
  const int b0 = blockIdx.x * 256;
  const int n0 = blockIdx.y * 64;
  const int mw = wave >> 1;
  const int nw = wave & 1;
  const int l15 = lane & 15;
  const int l4  = lane >> 4;
  const int rl  = lane >> 2;
  const int gq  = lane & 3;
  const int scol_sw = ((gq ^ ((rl >> 1) & 3)) << 4);

  // staging descriptors: 20 issues, wave + 8j (j<3, valid if i<20)
  const char* gbase[3];
  int loff[3];
  bool val[3];
#pragma unroll
  for (int j = 0; j < 3; ++j) {
    const int i = wave + (j << 3);
    val[j] = (i < 20);
    int grow = 0, lrow = 0;
    const unsigned short* gb = Hin;
    if (i < 16)      { grow = b0 + (i << 4) + rl; gb = Hin; lrow = (i << 4); }
    else if (i < 20) { const int is = i - 16; grow = n0 + (is << 4) + rl; gb = Wl; lrow = 256 + (is << 4); }
    gbase[j] = (const char*)gb + (size_t)grow * 512;
    loff[j]  = lrow << 6;
  }

  f32x4 acc[4][2];
#pragma unroll
  for (int a = 0; a < 4; ++a) { acc[a][0] = 0.f; acc[a][1] = 0.f; }

  {
    const int cb = scol_sw;
#pragma unroll
    for (int j = 0; j < 3; ++j) if (val[j]) gload16(gbase[j] + cb, (char*)sm + loff[j]);
  }
  __syncthreads();

#pragma unroll
  for (int k = 0; k < 8; ++k) {
    if (k < 7) {
      const int cb = ((k + 1) << 6) + scol_sw;
      char* lb = (char*)sm + ((k + 1) & 1) * 20480;
#pragma unroll
      for (int j = 0; j < 3; ++j) if (val[j]) gload16(gbase[j] + cb, lb + loff[j]);
    }

    const int bb = (k & 1) * 10240;

    bf16x8 a[4];
#pragma unroll
    for (int mt = 0; mt < 4; ++mt) {
      const int m = mw * 64 + mt * 16 + l15;
      a[mt] = *(const bf16x8*)&sm[bb + m * 32 + ((l4 ^ ((m >> 1) & 3)) << 3)];
    }
#pragma unroll
    for (int nt = 0; nt < 2; ++nt) {
      const int rw = nw * 32 + nt * 16 + l15;
      bf16x8 w = *(const bf16x8*)&sm[bb + (256 + rw) * 32 + ((l4 ^ ((rw >> 1) & 3)) << 3)];
#pragma unroll
      for (int mt = 0; mt < 4; ++mt)
        acc[mt][nt] = __builtin_amdgcn_mfma_f32_16x16x32_bf16(a[mt], w, acc[mt][nt], 0, 0, 0);
    }
    __syncthreads();
  }

#pragma unroll
  for (int nt = 0; nt < 2; ++nt) {
    const int d = n0 + nw * 32 + nt * 16 + l15;
    const float bl = blin[d];
#pragma unroll
    for (int mt = 0; mt < 4; ++mt) {
#pragma unroll
      for (int r = 0; r < 4; ++r) {
        const int b = b0 + mw * 64 + mt * 16 + l4 * 4 + r;
        const size_t off = (size_t)b * 256 + d;
        const float y = acc[mt][nt][r] + bl;
        Y[off]  = y;
        Xb[off] = f2bf(y);
      }
    }
  }
}

// ---------- launch ----------
extern "C" void kernel_launch(void* const* d_in, const int* in_sizes, int n_in,
                              void* d_out, int out_size, void* d_ws, size_t ws_size,
                              hipStream_t stream) {
  (void)in_sizes; (void)n_in; (void)out_size; (void)ws_size;
  const float* y0   = (const float*)d_in[0];
  const float* h0   = (const float*)d_in[1];
  const float* wih  = (const float*)d_in[2];
  const float* whh  = (const float*)d_in[3];
  const float* bih  = (const float*)d_in[4];
  const float* bhh  = (const float*)d_in[5];
  const float* wlin = (const float*)d_in[6];
  const float* blin = (const float*)d_in[7];
  float* out = (float*)d_out;

  // allow 114688 B dynamic LDS (host-side attr set; capture-safe, idempotent)
  static bool attr_done = false;
  if (!attr_done) {
    hipFuncSetAttribute((const void*)gru_layer,
                        hipFuncAttributeMaxDynamicSharedMemorySize, 114688);
    attr_done = true;
  }

  // ws layout (needs ~77.2 MB)
  char* ws = (char*)d_ws;
  unsigned short* wih_b  = (unsigned short*)ws;          // 2*768*256 el
  unsigned short* whh_b  = wih_b + 393216;
  unsigned short* wlin_b = whh_b + 393216;               // 65536 el
  float*          hf     = (float*)(ws + 1703936);       // [2][B][256] fp32
  unsigned short* hb     = (unsigned short*)(ws + 1703936 + 33554432); // [2 ping][2 layer][B][256] bf16
  unsigned short* xb     = hb + 16777216;                // [B][256] bf16

  prep<<<1024, 256, 0, stream>>>(y0, h0, wih, whh, wlin, wih_b, whh_b, wlin_b, hf, hb, xb);

  const size_t HB = (size_t)BATCH * 256;
  int cur = 0;
  for (int t = 0; t < HORIZON; ++t) {
    const int nxt = cur ^ 1;
    gru_layer<<<dim3(64, 4), 512, 114688, stream>>>(
        xb, hb + (size_t)(cur * 2 + 0) * HB, hb + (size_t)(nxt * 2 + 0) * HB, hf,
        wih_b, whh_b, bih, bhh);
    gru_layer<<<dim3(64, 4), 512, 114688, stream>>>(
        hb + (size_t)(nxt * 2 + 0) * HB, hb + (size_t)(cur * 2 + 1) * HB,
        hb + (size_t)(nxt * 2 + 1) * HB, hf + HB,
        wih_b + 196608, whh_b + 196608, bih + 768, bhh + 768);
    lin_out<<<dim3(64, 4), 512, 0, stream>>>(
        hb + (size_t)(nxt * 2 + 1) * HB, wlin_b, blin, out + (size_t)t * HB, xb);
    cur = nxt;
  }
}